// Round 20
// baseline (125.304 us; speedup 1.0000x reference)
//
#include <hip/hip_runtime.h>
#include <math.h>

#define BB 16
#define CC 256
#define NN 1024
#define DQK_ 64
#define DV_ 256
#define NR 192          // 3 * 64 (padded 63-entry tables)
#define EPS_F 1e-5f

// workspace offsets (float units)
#define OFF_XT  ((size_t)0)           // bf16 [B][N][C]   = 2097152 f
#define OFF_QB  ((size_t)2097152)     // bf16 [B][N][64]  = 524288 f
#define OFF_KB  ((size_t)2621440)     // bf16 [B][N][64]  = 524288 f
#define OFF_HT  ((size_t)2097152)     // bf16 [B][N][C], overlays QB/KB (dead after k_attn)
#define OFF_VB  ((size_t)6291456)     // bf16 [B][DV][N]  = 2097152 f
#define OFF_ATT ((size_t)8388608)     // bf16 [B][N][N]   = 8388608 f (transposed [b][m][n])
#define OFF_T   ((size_t)8388608)     // bf16 [B][C][N], overlays ATT (dead after k_pv)
#define OFF_WQK ((size_t)16777216)    // bf16 [128][256]
#define OFF_WV  ((size_t)16793600)    // bf16 [256][256]
#define OFF_WT  ((size_t)16826368)    // bf16 [256][256]
#define OFF_LTB ((size_t)16859136)    // bf16 [192][64] concat rel tables
#define OFF_BNS ((size_t)16865280)
#define OFF_BNQ ((size_t)16865536)
// total 16865792 f = 67.5 MB

typedef __attribute__((ext_vector_type(8))) short short8;
typedef __attribute__((ext_vector_type(4))) float f32x4;

__device__ __forceinline__ unsigned short f2b(float f) {
    unsigned int u = __float_as_uint(f);
    u = u + 0x7fffu + ((u >> 16) & 1u);      // RNE
    return (unsigned short)(u >> 16);
}
__device__ __forceinline__ float b2f(unsigned short s) {
    return __uint_as_float(((unsigned int)s) << 16);
}

// ---------------------------------------------------------------------------
// K0 (merged prep + xt): blocks 0..1023 = x->xT transpose; 1024..1196 = weight
// conversion (incl. LTb rel tables, bn zeroing).
__global__ __launch_bounds__(256) void k_prepxt(
    const float* __restrict__ x, unsigned short* __restrict__ xT,
    const float* __restrict__ qw, const float* __restrict__ kw,
    const float* __restrict__ vw, const float* __restrict__ tw,
    const float* __restrict__ xlt, const float* __restrict__ ylt,
    const float* __restrict__ zlt,
    unsigned short* __restrict__ Wqk, unsigned short* __restrict__ Wv,
    unsigned short* __restrict__ Wt, unsigned short* __restrict__ LTb,
    float* __restrict__ bnS, float* __restrict__ bnQ)
{
    const int tid = threadIdx.x;
    if (blockIdx.x < 1024) {
        __shared__ float tile[64][68];
        const int id = blockIdx.x;
        const int n0 = (id & 15) * 64;
        const int c0 = ((id >> 4) & 3) * 64;
        const int b  = id >> 6;
        #pragma unroll
        for (int it = 0; it < 4; ++it) {
            const int r = it * 16 + (tid >> 4);
            const int c4 = (tid & 15) * 4;
            *(float4*)&tile[r][c4] =
                *(const float4*)(x + ((size_t)b * CC + c0 + r) * NN + n0 + c4);
        }
        __syncthreads();
        const int n = tid >> 2;
        const int cg2 = (tid & 3) * 16;
        alignas(16) unsigned short buf[16];
        #pragma unroll
        for (int j = 0; j < 16; ++j) buf[j] = f2b(tile[cg2 + j][n]);
        unsigned short* dst = xT + ((size_t)b * NN + n0 + n) * CC + c0 + cg2;
        *(short8*)dst       = *(const short8*)&buf[0];
        *(short8*)(dst + 8) = *(const short8*)&buf[8];
        return;
    }
    const int pid = blockIdx.x - 1024;     // 0..172
    if (pid == 160) {
        bnS[tid] = 0.f;
        bnQ[tid] = 0.f;
        return;
    }
    if (pid > 160) {
        const int o2 = (pid - 161) * 256 + tid;   // quad idx < 3072
        const int e = o2 * 4;
        const int r = e >> 6, d = e & 63;
        const int a = r >> 6, q = r & 63;
        ushort4 u;
        if (q < 63) {
            const float* lt = (a == 0) ? xlt : ((a == 1) ? ylt : zlt);
            const float4 v = *(const float4*)(lt + q * 64 + d);
            u.x = f2b(v.x); u.y = f2b(v.y); u.z = f2b(v.z); u.w = f2b(v.w);
        } else {
            u.x = u.y = u.z = u.w = 0;
        }
        *(ushort4*)(LTb + e) = u;
        return;
    }
    const int o = pid * 256 + tid;   // quad index, 40960 total
    const float* src; unsigned short* dst;
    if (o < 8192) {
        const int e = o * 4;
        src = (e < 16384) ? (qw + e) : (kw + e - 16384);
        dst = Wqk + e;
    } else if (o < 24576) {
        const int e = (o - 8192) * 4;
        src = vw + e; dst = Wv + e;
    } else {
        const int e = (o - 24576) * 4;
        src = tw + e; dst = Wt + e;
    }
    const float4 v = *(const float4*)src;
    ushort4 u;
    u.x = f2b(v.x); u.y = f2b(v.y); u.z = f2b(v.z); u.w = f2b(v.w);
    *(ushort4*)dst = u;
}

// ---------------------------------------------------------------------------
// K1: Q,K projection via MFMA (V moved into the attn launch).
__global__ __launch_bounds__(256) void k_proj(
    const unsigned short* __restrict__ xT, const unsigned short* __restrict__ Wqk,
    unsigned short* __restrict__ Qb, unsigned short* __restrict__ Kb)
{
    const int b = blockIdx.y;
    const int n0 = blockIdx.x * 32;
    const int tid = threadIdx.x;
    const int l = tid & 63, w = tid >> 6;
    const int l15 = l & 15, l4 = l >> 4;
    f32x4 z = {0.f, 0.f, 0.f, 0.f};
    const int ng = (w >> 1) * 16, wh = (w & 1) * 64;
    const unsigned short* ap = xT + ((size_t)b * NN + n0 + ng + l15) * CC + l4 * 8;
    const unsigned short* bp = Wqk + ((size_t)(wh + l15)) * CC + l4 * 8;
    f32x4 acc[4] = {z, z, z, z};
    #pragma unroll 2
    for (int kk = 0; kk < CC; kk += 32) {
        const short8 a = *(const short8*)(ap + kk);
        short8 bf[4];
        #pragma unroll
        for (int j = 0; j < 4; ++j)
            bf[j] = *(const short8*)(bp + (size_t)j * 16 * CC + kk);
        #pragma unroll
        for (int j = 0; j < 4; ++j)
            acc[j] = __builtin_amdgcn_mfma_f32_16x16x32_bf16(a, bf[j], acc[j], 0, 0, 0);
    }
    #pragma unroll
    for (int j = 0; j < 4; ++j)
        #pragma unroll
        for (int r = 0; r < 4; ++r) {
            const int n = n0 + ng + l4 * 4 + r;
            const int ch = wh + j * 16 + l15;
            const unsigned short v = f2b(acc[j][r]);
            if (ch < 64) Qb[((size_t)b * NN + n) * DQK_ + ch] = v;
            else         Kb[((size_t)b * NN + n) * DQK_ + ch - 64] = v;
        }
}

// ---------------------------------------------------------------------------
// K3 (merged attn + V-proj): blockIdx.x < 64 -> attention for 16 q-rows;
// blockIdx.x >= 64 -> V projection (8 waves: dv-quadrant (w&3)*64,
// n-half (w>>2)*32, n0 = (bx-64)*64).  V is first consumed by k_pv, so
// co-scheduling it under the latency-bound attn blocks hides it entirely.
__global__ __launch_bounds__(512) void k_attn(
    const unsigned short* __restrict__ Qb, const unsigned short* __restrict__ Kb,
    const unsigned short* __restrict__ LTb, const int* __restrict__ disc,
    const unsigned short* __restrict__ Wv, const unsigned short* __restrict__ xT,
    const float* __restrict__ vb, unsigned short* __restrict__ Vb,
    unsigned short* __restrict__ att)
{
    __shared__ float QLs[16][193];
    __shared__ int   dmp[1024];
    __shared__ float redS[8][16];
    const int b = blockIdx.y;
    const int tid = threadIdx.x;
    const int l = tid & 63, w = tid >> 6;
    const int l15 = l & 15, l4 = l >> 4;

    if (blockIdx.x >= 64) {
        // ---- V projection path ----
        const int n0 = (blockIdx.x - 64) * 64;
        const int wd = (w & 3) * 64, wn2 = (w >> 2) * 32;
        const unsigned short* ap = Wv + ((size_t)(wd + l15)) * CC + l4 * 8;
        const unsigned short* bp = xT + ((size_t)b * NN + n0 + wn2 + l15) * CC + l4 * 8;
        f32x4 z = {0.f, 0.f, 0.f, 0.f};
        f32x4 acc[4][2] = {{z, z}, {z, z}, {z, z}, {z, z}};
        #pragma unroll 2
        for (int kk = 0; kk < CC; kk += 32) {
            short8 af[4], bf[2];
            #pragma unroll
            for (int i = 0; i < 4; ++i)
                af[i] = *(const short8*)(ap + (size_t)i * 16 * CC + kk);
            #pragma unroll
            for (int j = 0; j < 2; ++j)
                bf[j] = *(const short8*)(bp + (size_t)j * 16 * CC + kk);
            #pragma unroll
            for (int i = 0; i < 4; ++i)
                #pragma unroll
                for (int j = 0; j < 2; ++j)
                    acc[i][j] = __builtin_amdgcn_mfma_f32_16x16x32_bf16(af[i], bf[j], acc[i][j], 0, 0, 0);
        }
        #pragma unroll
        for (int i = 0; i < 4; ++i)
            #pragma unroll
            for (int r = 0; r < 4; ++r) {
                const int dv = wd + i * 16 + l4 * 4 + r;
                const float bias = vb[dv];
                #pragma unroll
                for (int j = 0; j < 2; ++j) {
                    const int n = n0 + wn2 + j * 16 + l15;
                    Vb[((size_t)b * DV_ + dv) * NN + n] = f2b(acc[i][j][r] + bias);
                }
            }
        return;
    }

    // ---- attention path ----
    const int q0 = blockIdx.x * 16;

    for (int m = tid; m < NN; m += 512) {
        const size_t base = ((size_t)b * NN + m) * 3;
        dmp[m] = disc[base] | (disc[base + 1] << 8) | (disc[base + 2] << 16);
    }

    const int q = q0 + l15;
    const int dn0 = disc[((size_t)b * NN + q) * 3 + 0] - 31;
    const int dn1 = disc[((size_t)b * NN + q) * 3 + 1] - 31;
    const int dn2 = disc[((size_t)b * NN + q) * 3 + 2] - 31;

    const unsigned short* qp = Qb + ((size_t)b * NN + q) * DQK_ + l4 * 8;
    const short8 qf0 = *(const short8*)qp;
    const short8 qf1 = *(const short8*)(qp + 32);

    // in-block QL: waves 0-5 compute 2 LT tiles each
    if (w < 6) {
        #pragma unroll
        for (int jj = 0; jj < 2; ++jj) {
            const int j = w * 2 + jj;
            const unsigned short* bp2 = LTb + (size_t)(j * 16 + l15) * DQK_ + l4 * 8;
            const short8 b0 = *(const short8*)bp2;
            const short8 b1 = *(const short8*)(bp2 + 32);
            f32x4 a2 = {0.f, 0.f, 0.f, 0.f};
            a2 = __builtin_amdgcn_mfma_f32_16x16x32_bf16(qf0, b0, a2, 0, 0, 0);
            a2 = __builtin_amdgcn_mfma_f32_16x16x32_bf16(qf1, b1, a2, 0, 0, 0);
            #pragma unroll
            for (int rr = 0; rr < 4; ++rr)
                QLs[l4 * 4 + rr][j * 16 + l15] = a2[rr];
        }
    }
    __syncthreads();

    const unsigned short* kbase = Kb + (size_t)b * NN * DQK_ + l4 * 8;
    const unsigned short* kp0 = kbase + (size_t)(w * 16 + l15) * DQK_;
    short8 kf0 = *(const short8*)kp0;
    short8 kf1 = *(const short8*)(kp0 + 32);
    int4 pmc = *(const int4*)&dmp[w * 16 + l4 * 4];

    float s[32];
    float sum4[4] = {0.f, 0.f, 0.f, 0.f};
    #pragma unroll
    for (int t = 0; t < 8; ++t) {
        const int tn = (t < 7) ? t + 1 : 7;
        const unsigned short* kpn = kbase + (size_t)(tn * 128 + w * 16 + l15) * DQK_;
        const short8 nf0 = *(const short8*)kpn;
        const short8 nf1 = *(const short8*)(kpn + 32);
        const int4 pmn = *(const int4*)&dmp[tn * 128 + w * 16 + l4 * 4];
        __builtin_amdgcn_s_setprio(1);
        f32x4 acc = {0.f, 0.f, 0.f, 0.f};
        acc = __builtin_amdgcn_mfma_f32_16x16x32_bf16(kf0, qf0, acc, 0, 0, 0);
        acc = __builtin_amdgcn_mfma_f32_16x16x32_bf16(kf1, qf1, acc, 0, 0, 0);
        __builtin_amdgcn_s_setprio(0);
        const int* pmp = (const int*)&pmc;
        #pragma unroll
        for (int r = 0; r < 4; ++r) {
            const int pm = pmp[r];
            const int i0 = (pm & 255) - dn0;
            const int i1 = ((pm >> 8) & 255) - dn1;
            const int i2 = (pm >> 16) - dn2;
            const float rel = QLs[l15][i0] + QLs[l15][64 + i1] + QLs[l15][128 + i2];
            const float e = __expf((acc[r] + rel) * 0.03125f);
            s[t * 4 + r] = e;
            sum4[r] += e;
        }
        kf0 = nf0; kf1 = nf1; pmc = pmn;
    }

    float sum = (sum4[0] + sum4[1]) + (sum4[2] + sum4[3]);
    sum += __shfl_xor(sum, 16);
    sum += __shfl_xor(sum, 32);
    if (l < 16) redS[w][l] = sum;
    __syncthreads();
    float tot = redS[0][l15];
    #pragma unroll
    for (int ww = 1; ww < 8; ++ww) tot += redS[ww][l15];
    const float inv = 1.0f / tot;

    #pragma unroll
    for (int t = 0; t < 8; ++t)
        #pragma unroll
        for (int r = 0; r < 4; ++r) {
            const int m = t * 128 + w * 16 + l4 * 4 + r;
            att[((size_t)b * NN + m) * NN + q] = f2b(s[t * 4 + r] * inv);
        }
}

// ---------------------------------------------------------------------------
// K4: XR^T + fused H^T = x^T - XR^T (bf16).  Double-buffered LDS GEMM
// (128x128, BK=64, reg-staged; LDS rows padded to 72 = 9x16B).
__global__ __launch_bounds__(256) void k_pv(
    const unsigned short* __restrict__ att, const unsigned short* __restrict__ Vb,
    const unsigned short* __restrict__ xT, unsigned short* __restrict__ HT)
{
    __shared__ unsigned short As[2][128][72];
    __shared__ unsigned short Bs[2][128][72];
    const int b = blockIdx.z;
    const int d0 = blockIdx.y * 128;
    const int m0 = blockIdx.x * 128;
    const int tid = threadIdx.x;
    const int l = tid & 63, w = tid >> 6;
    const int l15 = l & 15, l4 = l >> 4;
    const int wm = (w & 1) * 64, wd = (w >> 1) * 64;

    const unsigned short* agbase = att + ((size_t)b * NN + m0) * NN;
    const unsigned short* bgbase = Vb + ((size_t)b * DV_ + d0) * NN;

    f32x4 z = {0.f, 0.f, 0.f, 0.f};
    f32x4 acc[4][4];
    #pragma unroll
    for (int i = 0; i < 4; ++i)
        #pragma unroll
        for (int j = 0; j < 4; ++j) acc[i][j] = z;

    short8 pa[4], pb[4];
    #pragma unroll
    for (int it = 0; it < 4; ++it) {
        const int f = it * 256 + tid, r = f >> 3, c = (f & 7) * 8;
        pa[it] = *(const short8*)(agbase + (size_t)r * NN + c);
        pb[it] = *(const short8*)(bgbase + (size_t)r * NN + c);
    }
    #pragma unroll
    for (int it = 0; it < 4; ++it) {
        const int f = it * 256 + tid, r = f >> 3, c = (f & 7) * 8;
        *(short8*)&As[0][r][c] = pa[it];
        *(short8*)&Bs[0][r][c] = pb[it];
    }
    __syncthreads();

    for (int ks = 0; ks < 16; ++ks) {
        const int cur = ks & 1;
        if (ks < 15) {
            const int nk = (ks + 1) * 64;
            #pragma unroll
            for (int it = 0; it < 4; ++it) {
                const int f = it * 256 + tid, r = f >> 3, c = (f & 7) * 8;
                pa[it] = *(const short8*)(agbase + (size_t)r * NN + nk + c);
                pb[it] = *(const short8*)(bgbase + (size_t)r * NN + nk + c);
            }
        }
        #pragma unroll
        for (int ksub = 0; ksub < 2; ++ksub) {
            short8 af[4], bf[4];
            #pragma unroll
            for (int i = 0; i < 4; ++i)
                af[i] = *(const short8*)&As[cur][wm + i * 16 + l15][ksub * 32 + l4 * 8];
            #pragma unroll
            for (int j = 0; j < 4; ++j)
                bf[j] = *(const short8*)&Bs[cur][wd + j * 16 + l15][ksub * 32 + l4 * 8];
            #pragma unroll
            for (int i = 0; i < 4; ++i)
                #pragma unroll
                for (int j = 0; j < 4; ++j)
                    acc[i][j] = __builtin_amdgcn_mfma_f32_16x16x32_bf16(af[i], bf[j], acc[i][j], 0, 0, 0);
        }
        if (ks < 15) {
            #pragma unroll
            for (int it = 0; it < 4; ++it) {
                const int f = it * 256 + tid, r = f >> 3, c = (f & 7) * 8;
                *(short8*)&As[cur ^ 1][r][c] = pa[it];
                *(short8*)&Bs[cur ^ 1][r][c] = pb[it];
            }
        }
        __syncthreads();
    }

    #pragma unroll
    for (int i = 0; i < 4; ++i)
        #pragma unroll
        for (int r = 0; r < 4; ++r) {
            const int m = m0 + wm + i * 16 + l4 * 4 + r;
            const unsigned short* xrow = xT + ((size_t)b * NN + m) * CC;
            unsigned short* hrow = HT + ((size_t)b * NN + m) * CC;
            #pragma unroll
            for (int j = 0; j < 4; ++j) {
                const int dv = d0 + wd + j * 16 + l15;
                hrow[dv] = f2b(b2f(xrow[dv]) - acc[i][j][r]);
            }
        }
}

// ---------------------------------------------------------------------------
// K5: T[c][n] (bf16) = sum_d Wt[c][d] H^T[n][d] + tb; BN partial sums (f32).
__global__ __launch_bounds__(256) void k_trans(
    const unsigned short* __restrict__ Wt, const unsigned short* __restrict__ HT,
    const float* __restrict__ tb, unsigned short* __restrict__ T,
    float* __restrict__ bnS, float* __restrict__ bnQ)
{
    __shared__ float sS[128], sQ[128];
    const int b = blockIdx.z;
    const int c0 = blockIdx.y * 128;
    const int n0 = blockIdx.x * 64;
    const int tid = threadIdx.x;
    const int l = tid & 63, w = tid >> 6;
    const int l15 = l & 15, l4 = l >> 4;
    const int wc = (w & 1) * 64, wn = (w >> 1) * 32;
    if (tid < 128) { sS[tid] = 0.f; sQ[tid] = 0.f; }
    __syncthreads();
    const unsigned short* ap = Wt + ((size_t)(c0 + wc + l15)) * CC + l4 * 8;
    const unsigned short* bp = HT + ((size_t)b * NN + n0 + wn + l15) * CC + l4 * 8;
    f32x4 z = {0.f, 0.f, 0.f, 0.f};
    f32x4 acc[4][2] = {{z, z}, {z, z}, {z, z}, {z, z}};
    #pragma unroll 2
    for (int kk = 0; kk < CC; kk += 32) {
        short8 af[4], bf[2];
        #pragma unroll
        for (int i = 0; i < 4; ++i)
            af[i] = *(const short8*)(ap + (size_t)i * 16 * CC + kk);
        #pragma unroll
        for (int j = 0; j < 2; ++j)
            bf[j] = *(const short8*)(bp + (size_t)j * 16 * CC + kk);
        #pragma unroll
        for (int i = 0; i < 4; ++i)
            #pragma unroll
            for (int j = 0; j < 2; ++j)
                acc[i][j] = __builtin_amdgcn_mfma_f32_16x16x32_bf16(af[i], bf[j], acc[i][j], 0, 0, 0);
    }
    #pragma unroll
    for (int i = 0; i < 4; ++i)
        #pragma unroll
        for (int r = 0; r < 4; ++r) {
            const int cl = wc + i * 16 + l4 * 4 + r;
            const int c = c0 + cl;
            const float bias = tb[c];
            float s = 0.f, q = 0.f;
            #pragma unroll
            for (int j = 0; j < 2; ++j) {
                const int n = n0 + wn + j * 16 + l15;
                const float t = acc[i][j][r] + bias;
                T[((size_t)b * CC + c) * NN + n] = f2b(t);
                s += t; q += t * t;
            }
            s += __shfl_xor(s, 1); s += __shfl_xor(s, 2);
            s += __shfl_xor(s, 4); s += __shfl_xor(s, 8);
            q += __shfl_xor(q, 1); q += __shfl_xor(q, 2);
            q += __shfl_xor(q, 4); q += __shfl_xor(q, 8);
            if (l15 == 0) {
                atomicAdd(&sS[cl], s);
                atomicAdd(&sQ[cl], q);
            }
        }
    __syncthreads();
    if (tid < 128) {
        atomicAdd(&bnS[c0 + tid], sS[tid]);
        atomicAdd(&bnQ[c0 + tid], sQ[tid]);
    }
}

// ---------------------------------------------------------------------------
// K6: out = x + relu(bn(T)).  8 elems/thread; grid = B*C*N/8/256 = 2048.
__global__ __launch_bounds__(256) void k_out(
    const float* __restrict__ x, const unsigned short* __restrict__ T,
    const float* __restrict__ gamma, const float* __restrict__ beta,
    const float* __restrict__ bnS, const float* __restrict__ bnQ,
    float* __restrict__ out)
{
    const int i8 = blockIdx.x * 256 + threadIdx.x;   // 8-elem chunk index
    const int c = (i8 >> 7) & 255;
    const float meanv = bnS[c] * (1.0f / 16384.0f);
    const float varv  = bnQ[c] * (1.0f / 16384.0f) - meanv * meanv;
    const float inv   = rsqrtf(varv + EPS_F);
    const float g = gamma[c] * inv;
    const float be = beta[c];
    const short8 t8 = *(const short8*)(T + (size_t)i8 * 8);
    const unsigned short* tp = (const unsigned short*)&t8;
    const float4 xa = *(const float4*)(x + (size_t)i8 * 8);
    const float4 xb = *(const float4*)(x + (size_t)i8 * 8 + 4);
    float4 oa, ob;
    oa.x = xa.x + fmaxf(g * (b2f(tp[0]) - meanv) + be, 0.0f);
    oa.y = xa.y + fmaxf(g * (b2f(tp[1]) - meanv) + be, 0.0f);
    oa.z = xa.z + fmaxf(g * (b2f(tp[2]) - meanv) + be, 0.0f);
    oa.w = xa.w + fmaxf(g * (b2f(tp[3]) - meanv) + be, 0.0f);
    ob.x = xb.x + fmaxf(g * (b2f(tp[4]) - meanv) + be, 0.0f);
    ob.y = xb.y + fmaxf(g * (b2f(tp[5]) - meanv) + be, 0.0f);
    ob.z = xb.z + fmaxf(g * (b2f(tp[6]) - meanv) + be, 0.0f);
    ob.w = xb.w + fmaxf(g * (b2f(tp[7]) - meanv) + be, 0.0f);
    *(float4*)(out + (size_t)i8 * 8)     = oa;
    *(float4*)(out + (size_t)i8 * 8 + 4) = ob;
}

// ---------------------------------------------------------------------------
extern "C" void kernel_launch(void* const* d_in, const int* in_sizes, int n_in,
                              void* d_out, int out_size, void* d_ws, size_t ws_size,
                              hipStream_t stream)
{
    const float* x     = (const float*)d_in[0];
    const int*   disc  = (const int*)d_in[1];
    // d_in[2] = xyz (unused)
    const float* qw    = (const float*)d_in[3];
    const float* kw    = (const float*)d_in[4];
    const float* vw    = (const float*)d_in[5];
    const float* vb    = (const float*)d_in[6];
    const float* tw    = (const float*)d_in[7];
    const float* tb    = (const float*)d_in[8];
    const float* gamma = (const float*)d_in[9];
    const float* beta  = (const float*)d_in[10];
    const float* xlt   = (const float*)d_in[11];
    const float* ylt   = (const float*)d_in[12];
    const float* zlt   = (const float*)d_in[13];
    float* ws  = (float*)d_ws;
    float* out = (float*)d_out;

    unsigned short* xT  = (unsigned short*)(ws + OFF_XT);
    unsigned short* Qb  = (unsigned short*)(ws + OFF_QB);
    unsigned short* Kbf = (unsigned short*)(ws + OFF_KB);
    unsigned short* HT  = (unsigned short*)(ws + OFF_HT);
    unsigned short* Vb  = (unsigned short*)(ws + OFF_VB);
    unsigned short* ATT = (unsigned short*)(ws + OFF_ATT);
    unsigned short* T   = (unsigned short*)(ws + OFF_T);
    unsigned short* Wqk = (unsigned short*)(ws + OFF_WQK);
    unsigned short* Wv  = (unsigned short*)(ws + OFF_WV);
    unsigned short* Wt  = (unsigned short*)(ws + OFF_WT);
    unsigned short* LTb = (unsigned short*)(ws + OFF_LTB);
    float*          bnS = ws + OFF_BNS;
    float*          bnQ = ws + OFF_BNQ;

    k_prepxt<<<dim3(1197), 256, 0, stream>>>(x, xT, qw, kw, vw, tw,
                                             xlt, ylt, zlt,
                                             Wqk, Wv, Wt, LTb, bnS, bnQ);
    k_proj  <<<dim3(32, 16), 256, 0, stream>>>(xT, Wqk, Qb, Kbf);
    k_attn  <<<dim3(80, 16), 512, 0, stream>>>(Qb, Kbf, LTb, disc,
                                               Wv, xT, vb, Vb, ATT);
    k_pv    <<<dim3(8, 2, 16), 256, 0, stream>>>(ATT, Vb, xT, HT);
    k_trans <<<dim3(16, 2, 16), 256, 0, stream>>>(Wt, HT, tb, T, bnS, bnQ);
    k_out   <<<dim3(2048), 256, 0, stream>>>(x, T, gamma, beta, bnS, bnQ, out);
}

// Round 21
// 116.722 us; speedup vs baseline: 1.0735x; 1.0735x over previous
//
#include <hip/hip_runtime.h>
#include <math.h>

#define BB 16
#define CC 256
#define NN 1024
#define DQK_ 64
#define DV_ 256
#define NR 192          // 3 * 64 (padded 63-entry tables)
#define EPS_F 1e-5f

// workspace offsets (float units)
#define OFF_XT  ((size_t)0)           // bf16 [B][N][C]   = 2097152 f
#define OFF_QB  ((size_t)2097152)     // bf16 [B][N][64]  = 524288 f
#define OFF_KB  ((size_t)2621440)     // bf16 [B][N][64]  = 524288 f
#define OFF_HT  ((size_t)2097152)     // bf16 [B][N][C], overlays QB/KB (dead after k_attn)
#define OFF_VB  ((size_t)6291456)     // bf16 [B][DV][N]  = 2097152 f
#define OFF_ATT ((size_t)8388608)     // bf16 [B][N][N]   = 8388608 f (transposed [b][m][n])
#define OFF_T   ((size_t)8388608)     // bf16 [B][C][N], overlays ATT (dead after k_pv)
#define OFF_WQK ((size_t)16777216)    // bf16 [128][256]
#define OFF_WV  ((size_t)16793600)    // bf16 [256][256]
#define OFF_WT  ((size_t)16826368)    // bf16 [256][256]
#define OFF_LTB ((size_t)16859136)    // bf16 [192][64] concat rel tables
#define OFF_BNS ((size_t)16865280)
#define OFF_BNQ ((size_t)16865536)
// total 16865792 f = 67.5 MB

typedef __attribute__((ext_vector_type(8))) short short8;
typedef __attribute__((ext_vector_type(4))) float f32x4;

__device__ __forceinline__ unsigned short f2b(float f) {
    unsigned int u = __float_as_uint(f);
    u = u + 0x7fffu + ((u >> 16) & 1u);      // RNE
    return (unsigned short)(u >> 16);
}
__device__ __forceinline__ float b2f(unsigned short s) {
    return __uint_as_float(((unsigned int)s) << 16);
}

// ---------------------------------------------------------------------------
// K0 (merged prep + xt): blocks 0..1023 = x->xT transpose; 1024..1196 = weight
// conversion (incl. LTb rel tables, bn zeroing).
__global__ __launch_bounds__(256) void k_prepxt(
    const float* __restrict__ x, unsigned short* __restrict__ xT,
    const float* __restrict__ qw, const float* __restrict__ kw,
    const float* __restrict__ vw, const float* __restrict__ tw,
    const float* __restrict__ xlt, const float* __restrict__ ylt,
    const float* __restrict__ zlt,
    unsigned short* __restrict__ Wqk, unsigned short* __restrict__ Wv,
    unsigned short* __restrict__ Wt, unsigned short* __restrict__ LTb,
    float* __restrict__ bnS, float* __restrict__ bnQ)
{
    const int tid = threadIdx.x;
    if (blockIdx.x < 1024) {
        __shared__ float tile[64][68];
        const int id = blockIdx.x;
        const int n0 = (id & 15) * 64;
        const int c0 = ((id >> 4) & 3) * 64;
        const int b  = id >> 6;
        #pragma unroll
        for (int it = 0; it < 4; ++it) {
            const int r = it * 16 + (tid >> 4);
            const int c4 = (tid & 15) * 4;
            *(float4*)&tile[r][c4] =
                *(const float4*)(x + ((size_t)b * CC + c0 + r) * NN + n0 + c4);
        }
        __syncthreads();
        const int n = tid >> 2;
        const int cg2 = (tid & 3) * 16;
        alignas(16) unsigned short buf[16];
        #pragma unroll
        for (int j = 0; j < 16; ++j) buf[j] = f2b(tile[cg2 + j][n]);
        unsigned short* dst = xT + ((size_t)b * NN + n0 + n) * CC + c0 + cg2;
        *(short8*)dst       = *(const short8*)&buf[0];
        *(short8*)(dst + 8) = *(const short8*)&buf[8];
        return;
    }
    const int pid = blockIdx.x - 1024;     // 0..172
    if (pid == 160) {
        bnS[tid] = 0.f;
        bnQ[tid] = 0.f;
        return;
    }
    if (pid > 160) {
        const int o2 = (pid - 161) * 256 + tid;   // quad idx < 3072
        const int e = o2 * 4;
        const int r = e >> 6, d = e & 63;
        const int a = r >> 6, q = r & 63;
        ushort4 u;
        if (q < 63) {
            const float* lt = (a == 0) ? xlt : ((a == 1) ? ylt : zlt);
            const float4 v = *(const float4*)(lt + q * 64 + d);
            u.x = f2b(v.x); u.y = f2b(v.y); u.z = f2b(v.z); u.w = f2b(v.w);
        } else {
            u.x = u.y = u.z = u.w = 0;
        }
        *(ushort4*)(LTb + e) = u;
        return;
    }
    const int o = pid * 256 + tid;   // quad index, 40960 total
    const float* src; unsigned short* dst;
    if (o < 8192) {
        const int e = o * 4;
        src = (e < 16384) ? (qw + e) : (kw + e - 16384);
        dst = Wqk + e;
    } else if (o < 24576) {
        const int e = (o - 8192) * 4;
        src = vw + e; dst = Wv + e;
    } else {
        const int e = (o - 24576) * 4;
        src = tw + e; dst = Wt + e;
    }
    const float4 v = *(const float4*)src;
    ushort4 u;
    u.x = f2b(v.x); u.y = f2b(v.y); u.z = f2b(v.z); u.w = f2b(v.w);
    *(ushort4*)dst = u;
}

// ---------------------------------------------------------------------------
// K1 (merged QK + V projection): z=0 -> Q,K; z=1 -> V.
__global__ __launch_bounds__(256) void k_proj(
    const unsigned short* __restrict__ xT, const unsigned short* __restrict__ Wqk,
    const unsigned short* __restrict__ Wv, const float* __restrict__ vb,
    unsigned short* __restrict__ Qb, unsigned short* __restrict__ Kb,
    unsigned short* __restrict__ Vb)
{
    const int b = blockIdx.y;
    const int n0 = blockIdx.x * 32;
    const int tid = threadIdx.x;
    const int l = tid & 63, w = tid >> 6;
    const int l15 = l & 15, l4 = l >> 4;
    f32x4 z = {0.f, 0.f, 0.f, 0.f};
    if (blockIdx.z == 0) {
        const int ng = (w >> 1) * 16, wh = (w & 1) * 64;
        const unsigned short* ap = xT + ((size_t)b * NN + n0 + ng + l15) * CC + l4 * 8;
        const unsigned short* bp = Wqk + ((size_t)(wh + l15)) * CC + l4 * 8;
        f32x4 acc[4] = {z, z, z, z};
        #pragma unroll 2
        for (int kk = 0; kk < CC; kk += 32) {
            const short8 a = *(const short8*)(ap + kk);
            short8 bf[4];
            #pragma unroll
            for (int j = 0; j < 4; ++j)
                bf[j] = *(const short8*)(bp + (size_t)j * 16 * CC + kk);
            #pragma unroll
            for (int j = 0; j < 4; ++j)
                acc[j] = __builtin_amdgcn_mfma_f32_16x16x32_bf16(a, bf[j], acc[j], 0, 0, 0);
        }
        #pragma unroll
        for (int j = 0; j < 4; ++j)
            #pragma unroll
            for (int r = 0; r < 4; ++r) {
                const int n = n0 + ng + l4 * 4 + r;
                const int ch = wh + j * 16 + l15;
                const unsigned short v = f2b(acc[j][r]);
                if (ch < 64) Qb[((size_t)b * NN + n) * DQK_ + ch] = v;
                else         Kb[((size_t)b * NN + n) * DQK_ + ch - 64] = v;
            }
    } else {
        const unsigned short* ap = Wv + ((size_t)(w * 64 + l15)) * CC + l4 * 8;
        const unsigned short* bp = xT + ((size_t)b * NN + n0 + l15) * CC + l4 * 8;
        f32x4 acc[4][2] = {{z, z}, {z, z}, {z, z}, {z, z}};
        #pragma unroll 2
        for (int kk = 0; kk < CC; kk += 32) {
            short8 af[4], bf[2];
            #pragma unroll
            for (int i = 0; i < 4; ++i)
                af[i] = *(const short8*)(ap + (size_t)i * 16 * CC + kk);
            #pragma unroll
            for (int j = 0; j < 2; ++j)
                bf[j] = *(const short8*)(bp + (size_t)j * 16 * CC + kk);
            #pragma unroll
            for (int i = 0; i < 4; ++i)
                #pragma unroll
                for (int j = 0; j < 2; ++j)
                    acc[i][j] = __builtin_amdgcn_mfma_f32_16x16x32_bf16(af[i], bf[j], acc[i][j], 0, 0, 0);
        }
        #pragma unroll
        for (int i = 0; i < 4; ++i)
            #pragma unroll
            for (int r = 0; r < 4; ++r) {
                const int dv = w * 64 + i * 16 + l4 * 4 + r;
                const float bias = vb[dv];
                #pragma unroll
                for (int j = 0; j < 2; ++j) {
                    const int n = n0 + j * 16 + l15;
                    Vb[((size_t)b * DV_ + dv) * NN + n] = f2b(acc[i][j][r] + bias);
                }
            }
    }
}

// ---------------------------------------------------------------------------
// K3: energy (MFMA, swapped operands) + in-block QL + rel gathers + no-max
// softmax -> ATT_T bf16.  sum split into 4 independent partials, dmp int4
// prefetched with K fragments, s_setprio(1) around the MFMA pair.
__global__ __launch_bounds__(512) void k_attn(
    const unsigned short* __restrict__ Qb, const unsigned short* __restrict__ Kb,
    const unsigned short* __restrict__ LTb, const int* __restrict__ disc,
    unsigned short* __restrict__ att)
{
    __shared__ float QLs[16][193];
    __shared__ int   dmp[1024];
    __shared__ float redS[8][16];
    const int b = blockIdx.y;
    const int q0 = blockIdx.x * 16;
    const int tid = threadIdx.x;
    const int l = tid & 63, w = tid >> 6;
    const int l15 = l & 15, l4 = l >> 4;

    for (int m = tid; m < NN; m += 512) {
        const size_t base = ((size_t)b * NN + m) * 3;
        dmp[m] = disc[base] | (disc[base + 1] << 8) | (disc[base + 2] << 16);
    }

    const int q = q0 + l15;
    const int dn0 = disc[((size_t)b * NN + q) * 3 + 0] - 31;
    const int dn1 = disc[((size_t)b * NN + q) * 3 + 1] - 31;
    const int dn2 = disc[((size_t)b * NN + q) * 3 + 2] - 31;

    const unsigned short* qp = Qb + ((size_t)b * NN + q) * DQK_ + l4 * 8;
    const short8 qf0 = *(const short8*)qp;
    const short8 qf1 = *(const short8*)(qp + 32);

    // in-block QL: waves 0-5 compute 2 LT tiles each
    if (w < 6) {
        #pragma unroll
        for (int jj = 0; jj < 2; ++jj) {
            const int j = w * 2 + jj;
            const unsigned short* bp2 = LTb + (size_t)(j * 16 + l15) * DQK_ + l4 * 8;
            const short8 b0 = *(const short8*)bp2;
            const short8 b1 = *(const short8*)(bp2 + 32);
            f32x4 a2 = {0.f, 0.f, 0.f, 0.f};
            a2 = __builtin_amdgcn_mfma_f32_16x16x32_bf16(qf0, b0, a2, 0, 0, 0);
            a2 = __builtin_amdgcn_mfma_f32_16x16x32_bf16(qf1, b1, a2, 0, 0, 0);
            #pragma unroll
            for (int rr = 0; rr < 4; ++rr)
                QLs[l4 * 4 + rr][j * 16 + l15] = a2[rr];
        }
    }
    __syncthreads();

    const unsigned short* kbase = Kb + (size_t)b * NN * DQK_ + l4 * 8;
    const unsigned short* kp0 = kbase + (size_t)(w * 16 + l15) * DQK_;
    short8 kf0 = *(const short8*)kp0;
    short8 kf1 = *(const short8*)(kp0 + 32);
    int4 pmc = *(const int4*)&dmp[w * 16 + l4 * 4];

    float s[32];
    float sum4[4] = {0.f, 0.f, 0.f, 0.f};
    #pragma unroll
    for (int t = 0; t < 8; ++t) {
        const int tn = (t < 7) ? t + 1 : 7;
        const unsigned short* kpn = kbase + (size_t)(tn * 128 + w * 16 + l15) * DQK_;
        const short8 nf0 = *(const short8*)kpn;
        const short8 nf1 = *(const short8*)(kpn + 32);
        const int4 pmn = *(const int4*)&dmp[tn * 128 + w * 16 + l4 * 4];
        __builtin_amdgcn_s_setprio(1);
        f32x4 acc = {0.f, 0.f, 0.f, 0.f};
        acc = __builtin_amdgcn_mfma_f32_16x16x32_bf16(kf0, qf0, acc, 0, 0, 0);
        acc = __builtin_amdgcn_mfma_f32_16x16x32_bf16(kf1, qf1, acc, 0, 0, 0);
        __builtin_amdgcn_s_setprio(0);
        const int* pmp = (const int*)&pmc;
        #pragma unroll
        for (int r = 0; r < 4; ++r) {
            const int pm = pmp[r];
            const int i0 = (pm & 255) - dn0;
            const int i1 = ((pm >> 8) & 255) - dn1;
            const int i2 = (pm >> 16) - dn2;
            const float rel = QLs[l15][i0] + QLs[l15][64 + i1] + QLs[l15][128 + i2];
            const float e = __expf((acc[r] + rel) * 0.03125f);
            s[t * 4 + r] = e;
            sum4[r] += e;
        }
        kf0 = nf0; kf1 = nf1; pmc = pmn;
    }

    float sum = (sum4[0] + sum4[1]) + (sum4[2] + sum4[3]);
    sum += __shfl_xor(sum, 16);
    sum += __shfl_xor(sum, 32);
    if (l < 16) redS[w][l] = sum;
    __syncthreads();
    float tot = redS[0][l15];
    #pragma unroll
    for (int ww = 1; ww < 8; ++ww) tot += redS[ww][l15];
    const float inv = 1.0f / tot;

    #pragma unroll
    for (int t = 0; t < 8; ++t)
        #pragma unroll
        for (int r = 0; r < 4; ++r) {
            const int m = t * 128 + w * 16 + l4 * 4 + r;
            att[((size_t)b * NN + m) * NN + q] = f2b(s[t * 4 + r] * inv);
        }
}

// ---------------------------------------------------------------------------
// K4: XR^T + fused H^T = x^T - XR^T (bf16).  Double-buffered LDS GEMM
// (128x128, BK=64, reg-staged; LDS rows padded to 72 = 9x16B).
__global__ __launch_bounds__(256) void k_pv(
    const unsigned short* __restrict__ att, const unsigned short* __restrict__ Vb,
    const unsigned short* __restrict__ xT, unsigned short* __restrict__ HT)
{
    __shared__ unsigned short As[2][128][72];
    __shared__ unsigned short Bs[2][128][72];
    const int b = blockIdx.z;
    const int d0 = blockIdx.y * 128;
    const int m0 = blockIdx.x * 128;
    const int tid = threadIdx.x;
    const int l = tid & 63, w = tid >> 6;
    const int l15 = l & 15, l4 = l >> 4;
    const int wm = (w & 1) * 64, wd = (w >> 1) * 64;

    const unsigned short* agbase = att + ((size_t)b * NN + m0) * NN;
    const unsigned short* bgbase = Vb + ((size_t)b * DV_ + d0) * NN;

    f32x4 z = {0.f, 0.f, 0.f, 0.f};
    f32x4 acc[4][4];
    #pragma unroll
    for (int i = 0; i < 4; ++i)
        #pragma unroll
        for (int j = 0; j < 4; ++j) acc[i][j] = z;

    short8 pa[4], pb[4];
    #pragma unroll
    for (int it = 0; it < 4; ++it) {
        const int f = it * 256 + tid, r = f >> 3, c = (f & 7) * 8;
        pa[it] = *(const short8*)(agbase + (size_t)r * NN + c);
        pb[it] = *(const short8*)(bgbase + (size_t)r * NN + c);
    }
    #pragma unroll
    for (int it = 0; it < 4; ++it) {
        const int f = it * 256 + tid, r = f >> 3, c = (f & 7) * 8;
        *(short8*)&As[0][r][c] = pa[it];
        *(short8*)&Bs[0][r][c] = pb[it];
    }
    __syncthreads();

    for (int ks = 0; ks < 16; ++ks) {
        const int cur = ks & 1;
        if (ks < 15) {
            const int nk = (ks + 1) * 64;
            #pragma unroll
            for (int it = 0; it < 4; ++it) {
                const int f = it * 256 + tid, r = f >> 3, c = (f & 7) * 8;
                pa[it] = *(const short8*)(agbase + (size_t)r * NN + nk + c);
                pb[it] = *(const short8*)(bgbase + (size_t)r * NN + nk + c);
            }
        }
        #pragma unroll
        for (int ksub = 0; ksub < 2; ++ksub) {
            short8 af[4], bf[4];
            #pragma unroll
            for (int i = 0; i < 4; ++i)
                af[i] = *(const short8*)&As[cur][wm + i * 16 + l15][ksub * 32 + l4 * 8];
            #pragma unroll
            for (int j = 0; j < 4; ++j)
                bf[j] = *(const short8*)&Bs[cur][wd + j * 16 + l15][ksub * 32 + l4 * 8];
            #pragma unroll
            for (int i = 0; i < 4; ++i)
                #pragma unroll
                for (int j = 0; j < 4; ++j)
                    acc[i][j] = __builtin_amdgcn_mfma_f32_16x16x32_bf16(af[i], bf[j], acc[i][j], 0, 0, 0);
        }
        if (ks < 15) {
            #pragma unroll
            for (int it = 0; it < 4; ++it) {
                const int f = it * 256 + tid, r = f >> 3, c = (f & 7) * 8;
                *(short8*)&As[cur ^ 1][r][c] = pa[it];
                *(short8*)&Bs[cur ^ 1][r][c] = pb[it];
            }
        }
        __syncthreads();
    }

    #pragma unroll
    for (int i = 0; i < 4; ++i)
        #pragma unroll
        for (int r = 0; r < 4; ++r) {
            const int m = m0 + wm + i * 16 + l4 * 4 + r;
            const unsigned short* xrow = xT + ((size_t)b * NN + m) * CC;
            unsigned short* hrow = HT + ((size_t)b * NN + m) * CC;
            #pragma unroll
            for (int j = 0; j < 4; ++j) {
                const int dv = d0 + wd + j * 16 + l15;
                hrow[dv] = f2b(b2f(xrow[dv]) - acc[i][j][r]);
            }
        }
}

// ---------------------------------------------------------------------------
// K5: T[c][n] (bf16) = sum_d Wt[c][d] H^T[n][d] + tb; BN partial sums (f32).
__global__ __launch_bounds__(256) void k_trans(
    const unsigned short* __restrict__ Wt, const unsigned short* __restrict__ HT,
    const float* __restrict__ tb, unsigned short* __restrict__ T,
    float* __restrict__ bnS, float* __restrict__ bnQ)
{
    __shared__ float sS[128], sQ[128];
    const int b = blockIdx.z;
    const int c0 = blockIdx.y * 128;
    const int n0 = blockIdx.x * 64;
    const int tid = threadIdx.x;
    const int l = tid & 63, w = tid >> 6;
    const int l15 = l & 15, l4 = l >> 4;
    const int wc = (w & 1) * 64, wn = (w >> 1) * 32;
    if (tid < 128) { sS[tid] = 0.f; sQ[tid] = 0.f; }
    __syncthreads();
    const unsigned short* ap = Wt + ((size_t)(c0 + wc + l15)) * CC + l4 * 8;
    const unsigned short* bp = HT + ((size_t)b * NN + n0 + wn + l15) * CC + l4 * 8;
    f32x4 z = {0.f, 0.f, 0.f, 0.f};
    f32x4 acc[4][2] = {{z, z}, {z, z}, {z, z}, {z, z}};
    #pragma unroll 2
    for (int kk = 0; kk < CC; kk += 32) {
        short8 af[4], bf[2];
        #pragma unroll
        for (int i = 0; i < 4; ++i)
            af[i] = *(const short8*)(ap + (size_t)i * 16 * CC + kk);
        #pragma unroll
        for (int j = 0; j < 2; ++j)
            bf[j] = *(const short8*)(bp + (size_t)j * 16 * CC + kk);
        #pragma unroll
        for (int i = 0; i < 4; ++i)
            #pragma unroll
            for (int j = 0; j < 2; ++j)
                acc[i][j] = __builtin_amdgcn_mfma_f32_16x16x32_bf16(af[i], bf[j], acc[i][j], 0, 0, 0);
    }
    #pragma unroll
    for (int i = 0; i < 4; ++i)
        #pragma unroll
        for (int r = 0; r < 4; ++r) {
            const int cl = wc + i * 16 + l4 * 4 + r;
            const int c = c0 + cl;
            const float bias = tb[c];
            float s = 0.f, q = 0.f;
            #pragma unroll
            for (int j = 0; j < 2; ++j) {
                const int n = n0 + wn + j * 16 + l15;
                const float t = acc[i][j][r] + bias;
                T[((size_t)b * CC + c) * NN + n] = f2b(t);
                s += t; q += t * t;
            }
            s += __shfl_xor(s, 1); s += __shfl_xor(s, 2);
            s += __shfl_xor(s, 4); s += __shfl_xor(s, 8);
            q += __shfl_xor(q, 1); q += __shfl_xor(q, 2);
            q += __shfl_xor(q, 4); q += __shfl_xor(q, 8);
            if (l15 == 0) {
                atomicAdd(&sS[cl], s);
                atomicAdd(&sQ[cl], q);
            }
        }
    __syncthreads();
    if (tid < 128) {
        atomicAdd(&bnS[c0 + tid], sS[tid]);
        atomicAdd(&bnQ[c0 + tid], sQ[tid]);
    }
}

// ---------------------------------------------------------------------------
// K6: out = x + relu(bn(T)).  8 elems/thread; grid = B*C*N/8/256 = 2048.
__global__ __launch_bounds__(256) void k_out(
    const float* __restrict__ x, const unsigned short* __restrict__ T,
    const float* __restrict__ gamma, const float* __restrict__ beta,
    const float* __restrict__ bnS, const float* __restrict__ bnQ,
    float* __restrict__ out)
{
    const int i8 = blockIdx.x * 256 + threadIdx.x;   // 8-elem chunk index
    const int c = (i8 >> 7) & 255;
    const float meanv = bnS[c] * (1.0f / 16384.0f);
    const float varv  = bnQ[c] * (1.0f / 16384.0f) - meanv * meanv;
    const float inv   = rsqrtf(varv + EPS_F);
    const float g = gamma[c] * inv;
    const float be = beta[c];
    const short8 t8 = *(const short8*)(T + (size_t)i8 * 8);
    const unsigned short* tp = (const unsigned short*)&t8;
    const float4 xa = *(const float4*)(x + (size_t)i8 * 8);
    const float4 xb = *(const float4*)(x + (size_t)i8 * 8 + 4);
    float4 oa, ob;
    oa.x = xa.x + fmaxf(g * (b2f(tp[0]) - meanv) + be, 0.0f);
    oa.y = xa.y + fmaxf(g * (b2f(tp[1]) - meanv) + be, 0.0f);
    oa.z = xa.z + fmaxf(g * (b2f(tp[2]) - meanv) + be, 0.0f);
    oa.w = xa.w + fmaxf(g * (b2f(tp[3]) - meanv) + be, 0.0f);
    ob.x = xb.x + fmaxf(g * (b2f(tp[4]) - meanv) + be, 0.0f);
    ob.y = xb.y + fmaxf(g * (b2f(tp[5]) - meanv) + be, 0.0f);
    ob.z = xb.z + fmaxf(g * (b2f(tp[6]) - meanv) + be, 0.0f);
    ob.w = xb.w + fmaxf(g * (b2f(tp[7]) - meanv) + be, 0.0f);
    *(float4*)(out + (size_t)i8 * 8)     = oa;
    *(float4*)(out + (size_t)i8 * 8 + 4) = ob;
}

// ---------------------------------------------------------------------------
extern "C" void kernel_launch(void* const* d_in, const int* in_sizes, int n_in,
                              void* d_out, int out_size, void* d_ws, size_t ws_size,
                              hipStream_t stream)
{
    const float* x     = (const float*)d_in[0];
    const int*   disc  = (const int*)d_in[1];
    // d_in[2] = xyz (unused)
    const float* qw    = (const float*)d_in[3];
    const float* kw    = (const float*)d_in[4];
    const float* vw    = (const float*)d_in[5];
    const float* vb    = (const float*)d_in[6];
    const float* tw    = (const float*)d_in[7];
    const float* tb    = (const float*)d_in[8];
    const float* gamma = (const float*)d_in[9];
    const float* beta  = (const float*)d_in[10];
    const float* xlt   = (const float*)d_in[11];
    const float* ylt   = (const float*)d_in[12];
    const float* zlt   = (const float*)d_in[13];
    float* ws  = (float*)d_ws;
    float* out = (float*)d_out;

    unsigned short* xT  = (unsigned short*)(ws + OFF_XT);
    unsigned short* Qb  = (unsigned short*)(ws + OFF_QB);
    unsigned short* Kbf = (unsigned short*)(ws + OFF_KB);
    unsigned short* HT  = (unsigned short*)(ws + OFF_HT);
    unsigned short* Vb  = (unsigned short*)(ws + OFF_VB);
    unsigned short* ATT = (unsigned short*)(ws + OFF_ATT);
    unsigned short* T   = (unsigned short*)(ws + OFF_T);
    unsigned short* Wqk = (unsigned short*)(ws + OFF_WQK);
    unsigned short* Wv  = (unsigned short*)(ws + OFF_WV);
    unsigned short* Wt  = (unsigned short*)(ws + OFF_WT);
    unsigned short* LTb = (unsigned short*)(ws + OFF_LTB);
    float*          bnS = ws + OFF_BNS;
    float*          bnQ = ws + OFF_BNQ;

    k_prepxt<<<dim3(1197), 256, 0, stream>>>(x, xT, qw, kw, vw, tw,
                                             xlt, ylt, zlt,
                                             Wqk, Wv, Wt, LTb, bnS, bnQ);
    k_proj  <<<dim3(32, 16, 2), 256, 0, stream>>>(xT, Wqk, Wv, vb, Qb, Kbf, Vb);
    k_attn  <<<dim3(64, 16), 512, 0, stream>>>(Qb, Kbf, LTb, disc, ATT);
    k_pv    <<<dim3(8, 2, 16), 256, 0, stream>>>(ATT, Vb, xT, HT);
    k_trans <<<dim3(16, 2, 16), 256, 0, stream>>>(Wt, HT, tb, T, bnS, bnQ);
    k_out   <<<dim3(2048), 256, 0, stream>>>(x, T, gamma, beta, bnS, bnQ, out);
}